// Round 8
// baseline (297.934 us; speedup 1.0000x reference)
//
#include <hip/hip_runtime.h>

typedef unsigned short ushort_t;
typedef unsigned int uint_t;
typedef __attribute__((ext_vector_type(8))) short bf16x8;
typedef __attribute__((ext_vector_type(4))) float f32x4;

#define EPSV 1e-5f
#define LOG2E 1.4426950408889634f
#define QSC (0.17677669529663687f * LOG2E)   // (1/sqrt(32)) * log2(e)

__device__ __forceinline__ float u2f(uint_t x) { return __builtin_bit_cast(float, x); }
__device__ __forceinline__ uint_t f2u(float x) { return __builtin_bit_cast(uint_t, x); }
__device__ __forceinline__ float bflo(uint_t u) { return u2f(u << 16); }
__device__ __forceinline__ float bfhi(uint_t u) { return u2f(u & 0xFFFF0000u); }
__device__ __forceinline__ ushort_t f2bf(float f) {
    uint_t x = f2u(f);
    x += 0x7FFFu + ((x >> 16) & 1u);   // RNE
    return (ushort_t)(x >> 16);
}
__device__ __forceinline__ uint_t cvtpk(float lo, float hi) {
    uint_t r;
    asm("v_cvt_pk_bf16_f32 %0, %1, %2" : "=v"(r) : "v"(lo), "v"(hi));
    return r;
}
__device__ __forceinline__ float exp2v(float x) {
    float r;
    asm("v_exp_f32 %0, %1" : "=v"(r) : "v"(x));
    return r;
}
__device__ __forceinline__ float rcpv(float x) {
    float r;
    asm("v_rcp_f32 %0, %1" : "=v"(r) : "v"(x));
    return r;
}
__device__ __forceinline__ f32x4 mfma16(bf16x8 a, bf16x8 b, f32x4 c) {
    return __builtin_amdgcn_mfma_f32_16x16x32_bf16(a, b, c, 0, 0, 0);
}
__device__ __forceinline__ float wsum(float v) {
#pragma unroll
    for (int m = 32; m >= 1; m >>= 1) v += __shfl_xor(v, m, 64);
    return v;
}

// -------- K0: pack transposed bf16 weights: wtT[h][c(128)][k(256)], woT[c][k] --------
__global__ __launch_bounds__(256) void k_prep(const float* __restrict__ Wq, const float* __restrict__ Wk,
                                              const float* __restrict__ Wv, const float* __restrict__ Wg,
                                              const float* __restrict__ Wo,
                                              ushort_t* __restrict__ wtT, ushort_t* __restrict__ woT) {
    const int k = blockIdx.x, t = threadIdx.x;
    const int h = t >> 5, c = t & 31;
    wtT[(size_t)(h * 128 +   0 + c) * 256 + k] = f2bf(Wq[k * 256 + t]);
    wtT[(size_t)(h * 128 +  32 + c) * 256 + k] = f2bf(Wk[k * 256 + t]);
    wtT[(size_t)(h * 128 +  64 + c) * 256 + k] = f2bf(Wv[k * 256 + t]);
    wtT[(size_t)(h * 128 +  96 + c) * 256 + k] = f2bf(Wg[k * 256 + t]);
    woT[(size_t)t * 256 + k] = f2bf(Wo[k * 256 + t]);
}

// -------- K1: LayerNorm(m) -> mn (bf16) --------
__global__ __launch_bounds__(256) void k_ln_m(const float* __restrict__ m,
                                              const float* __restrict__ g,
                                              const float* __restrict__ b,
                                              ushort_t* __restrict__ mn) {
    const int lane = threadIdx.x & 63;
    const int row  = blockIdx.x * 4 + (threadIdx.x >> 6);
    const float4 x = *(const float4*)(m + (size_t)row * 256 + lane * 4);
    const float mu = wsum(x.x + x.y + x.z + x.w) * (1.f / 256.f);
    const float dx = x.x - mu, dy = x.y - mu, dz = x.z - mu, dw = x.w - mu;
    const float var = wsum(dx * dx + dy * dy + dz * dz + dw * dw) * (1.f / 256.f);
    const float rs = rsqrtf(var + EPSV);
    const float4 gg = *(const float4*)(g + lane * 4);
    const float4 bb = *(const float4*)(b + lane * 4);
    ushort4 o;
    o.x = f2bf(dx * rs * gg.x + bb.x);
    o.y = f2bf(dy * rs * gg.y + bb.y);
    o.z = f2bf(dz * rs * gg.z + bb.z);
    o.w = f2bf(dw * rs * gg.w + bb.w);
    *(ushort4*)(mn + (size_t)row * 256 + lane * 4) = o;
}

// -------- K2: LayerNorm(z) @ Wb -> pb[h][i][j] (f32, pre-scaled by log2e) --------
__global__ __launch_bounds__(256) void k_pair_bias(const float* __restrict__ z,
                                                   const float* __restrict__ g,
                                                   const float* __restrict__ b,
                                                   const float* __restrict__ Wb,
                                                   float* __restrict__ pb) {
    const int lane = threadIdx.x & 63;
    const int row  = blockIdx.x * 4 + (threadIdx.x >> 6);
    const float2 x = *(const float2*)(z + (size_t)row * 128 + lane * 2);
    const float mu = wsum(x.x + x.y) * (1.f / 128.f);
    const float d0 = x.x - mu, d1 = x.y - mu;
    const float var = wsum(d0 * d0 + d1 * d1) * (1.f / 128.f);
    const float rs = rsqrtf(var + EPSV);
    const float2 gg = *(const float2*)(g + lane * 2);
    const float2 bb = *(const float2*)(b + lane * 2);
    const float z0 = d0 * rs * gg.x + bb.x;
    const float z1 = d1 * rs * gg.y + bb.y;
    const float4 wa0 = *(const float4*)(Wb + lane * 16 + 0);
    const float4 wa1 = *(const float4*)(Wb + lane * 16 + 4);
    const float4 wb0 = *(const float4*)(Wb + lane * 16 + 8);
    const float4 wb1 = *(const float4*)(Wb + lane * 16 + 12);
    float p[8];
    p[0] = z0 * wa0.x + z1 * wb0.x;
    p[1] = z0 * wa0.y + z1 * wb0.y;
    p[2] = z0 * wa0.z + z1 * wb0.z;
    p[3] = z0 * wa0.w + z1 * wb0.w;
    p[4] = z0 * wa1.x + z1 * wb1.x;
    p[5] = z0 * wa1.y + z1 * wb1.y;
    p[6] = z0 * wa1.z + z1 * wb1.z;
    p[7] = z0 * wa1.w + z1 * wb1.w;
#pragma unroll
    for (int h = 0; h < 8; ++h) p[h] = wsum(p[h]);
    float v = p[0];
#pragma unroll
    for (int h = 1; h < 8; ++h) v = (lane == h) ? p[h] : v;
    if (lane < 8) pb[(size_t)lane * 65536 + row] = v * LOG2E;
}

// -------- K3: MFMA fused QKVG projection + attention (no-max softmax) + gate --------
// NOTE: keep __launch_bounds__ min-waves at 1. Empirical rule from R4/R6/R7 vs
// R2/R3/R5: every variant compiled with min-waves/EU >= 2 (VGPR cap <= 256,
// forcing AGPR/spill allocation) produced NaN; every min-waves==1 variant passed.
// Phase B is software-pipelined (depth-1 register double-buffering of K/V
// fragments and pair-bias loads) + setprio around MFMA clusters.
// blockIdx decode: n = bid & 255, h = bid >> 8 => all 8 heads of one n land on the
// same XCD (XCD = bid % 8 = n % 8), so mn[n] is fetched from HBM once, reused from L2.
__global__ __launch_bounds__(256, 1) void k_attn(const ushort_t* __restrict__ mn,
                                                 const ushort_t* __restrict__ wtT,
                                                 const float* __restrict__ pb,
                                                 const int* __restrict__ msa_mask,
                                                 const float* __restrict__ bg,
                                                 ushort_t* __restrict__ ao) {
    __shared__ ushort_t k_s[256 * 40];   // [j][c], 80B rows
    __shared__ ushort_t qp_s[256 * 40];  // Phase A: q[i][c]; Phase B (after q->regs): P[w][i64][j32] per wave
    __shared__ ushort_t vT[32 * 264];    // [c][j], later reused as gated-output transpose
    __shared__ ushort_t gT[32 * 264];    // [c][i], holds sigmoid gate (bf16)
    __shared__ float maskb[256];

    const int t = threadIdx.x;
    const int n = blockIdx.x & 255, h = blockIdx.x >> 8;
    const int w = t >> 6, l = t & 63;
    const int l16 = l & 15, g = l >> 4;

    maskb[t] = msa_mask[n * 256 + t] ? 0.f : -1.5e9f;
    const float bg0 = bg[h * 32 + l16];
    const float bg1 = bg[h * 32 + 16 + l16];

    const ushort_t* mb = mn + (size_t)n * 65536;
    const ushort_t* wb = wtT + (size_t)h * 128 * 256;

    // ---- Phase A: qkvg[i][c] = mn[i][:] @ W[:,c] via MFMA ----
#pragma unroll
    for (int chalf = 0; chalf < 2; ++chalf) {
        f32x4 acc[4][4];
#pragma unroll
        for (int rt = 0; rt < 4; ++rt)
#pragma unroll
            for (int ct = 0; ct < 4; ++ct) acc[rt][ct] = (f32x4){0.f, 0.f, 0.f, 0.f};

#pragma unroll
        for (int ks = 0; ks < 8; ++ks) {
            bf16x8 a[4], b[4];
#pragma unroll
            for (int rt = 0; rt < 4; ++rt)
                a[rt] = *(const bf16x8*)(mb + (size_t)(w * 64 + rt * 16 + l16) * 256 + ks * 32 + g * 8);
#pragma unroll
            for (int ct = 0; ct < 4; ++ct)
                b[ct] = *(const bf16x8*)(wb + (size_t)(chalf * 64 + ct * 16 + l16) * 256 + ks * 32 + g * 8);
#pragma unroll
            for (int rt = 0; rt < 4; ++rt)
#pragma unroll
                for (int ct = 0; ct < 4; ++ct)
                    acc[rt][ct] = mfma16(a[rt], b[ct], acc[rt][ct]);
        }
        // epilogue: C-frag lane holds [row = g*4+r][col = l16]
#pragma unroll
        for (int ct = 0; ct < 4; ++ct) {
            const int mat = chalf * 2 + (ct >> 1);       // 0 q, 1 k, 2 v, 3 g
            const int cc = (ct & 1) * 16 + l16;
#pragma unroll
            for (int rt = 0; rt < 4; ++rt) {
                const int i0 = w * 64 + rt * 16 + g * 4;
                const f32x4 v = acc[rt][ct];
                if (mat == 0) {          // q: fold SCALE*log2e
#pragma unroll
                    for (int r = 0; r < 4; ++r) qp_s[(i0 + r) * 40 + cc] = f2bf(v[r] * QSC);
                } else if (mat == 1) {   // k
#pragma unroll
                    for (int r = 0; r < 4; ++r) k_s[(i0 + r) * 40 + cc] = f2bf(v[r]);
                } else if (mat == 2) {   // v -> transposed
                    const uint_t lo = cvtpk(v[0], v[1]);
                    const uint_t hi = cvtpk(v[2], v[3]);
                    *(uint2*)(vT + cc * 264 + i0) = make_uint2(lo, hi);
                } else {                 // g -> sigmoid gate, transposed
                    const float bgc = (ct & 1) ? bg1 : bg0;
                    float gt[4];
#pragma unroll
                    for (int r = 0; r < 4; ++r)
                        gt[r] = rcpv(1.f + exp2v(-(v[r] + bgc) * LOG2E));
                    const uint_t lo = cvtpk(gt[0], gt[1]);
                    const uint_t hi = cvtpk(gt[2], gt[3]);
                    *(uint2*)(gT + cc * 264 + i0) = make_uint2(lo, hi);
                }
            }
        }
    }
    __syncthreads();

    // ---- Phase B: attention. Wave w owns rows i in [w*64, w*64+64). ----
    // Hoist q fragments to registers, then reuse qp_s rows [w*64, w*64+64) as the
    // wave-private P buffer (no barrier needed: same-wave producer/consumer).
    bf16x8 bq[4];
#pragma unroll
    for (int it = 0; it < 4; ++it)
        bq[it] = *(const bf16x8*)&qp_s[(w * 64 + it * 16 + l16) * 40 + g * 8];
    ushort_t* p_w = qp_s + w * 64 * 40;

    const float* pbh = pb + (size_t)h * 65536;
    f32x4 oT[2][4];
#pragma unroll
    for (int ct = 0; ct < 2; ++ct)
#pragma unroll
        for (int it = 0; it < 4; ++it) oT[ct][it] = (f32x4){0.f, 0.f, 0.f, 0.f};
    float lsum[4] = {0.f, 0.f, 0.f, 0.f};

    // pipeline prologue: K/V fragments + pair-bias for jc=0
    bf16x8 ak[2], av[2];
    f32x4 pc0[4], pc1[4];
#pragma unroll
    for (int jt = 0; jt < 2; ++jt)
        ak[jt] = *(const bf16x8*)&k_s[(jt * 16 + l16) * 40 + g * 8];
#pragma unroll
    for (int ct = 0; ct < 2; ++ct)
        av[ct] = *(const bf16x8*)&vT[(ct * 16 + l16) * 264 + g * 8];
#pragma unroll
    for (int it = 0; it < 4; ++it) {
        const int i = w * 64 + it * 16 + l16;
        pc0[it] = *(const f32x4*)(pbh + (size_t)i * 256 + g * 4);
        pc1[it] = *(const f32x4*)(pbh + (size_t)i * 256 + 16 + g * 4);
    }

    for (int jc = 0; jc < 8; ++jc) {
        // prefetch next iteration's K/V fragments + pair-bias (latency hides
        // under this iteration's S-MFMA + softmax + PV)
        bf16x8 akn[2], avn[2];
        f32x4 pn0[4], pn1[4];
        if (jc < 7) {
            const int j0 = (jc + 1) * 32;
#pragma unroll
            for (int jt = 0; jt < 2; ++jt)
                akn[jt] = *(const bf16x8*)&k_s[(j0 + jt * 16 + l16) * 40 + g * 8];
#pragma unroll
            for (int ct = 0; ct < 2; ++ct)
                avn[ct] = *(const bf16x8*)&vT[(ct * 16 + l16) * 264 + j0 + g * 8];
#pragma unroll
            for (int it = 0; it < 4; ++it) {
                const int i = w * 64 + it * 16 + l16;
                pn0[it] = *(const f32x4*)(pbh + (size_t)i * 256 + j0 + g * 4);
                pn1[it] = *(const f32x4*)(pbh + (size_t)i * 256 + j0 + 16 + g * 4);
            }
        }

        // S^T = mfma(K, Q): lane holds S[j = jc*32 + jt*16 + g*4 + r][i = it*16 + l16]
        f32x4 st[2][4];
        __builtin_amdgcn_s_setprio(1);
#pragma unroll
        for (int jt = 0; jt < 2; ++jt)
#pragma unroll
            for (int it = 0; it < 4; ++it)
                st[jt][it] = mfma16(ak[jt], bq[it], (f32x4){0.f, 0.f, 0.f, 0.f});
        __builtin_amdgcn_s_setprio(0);

        const f32x4 mk0 = *(const f32x4*)&maskb[jc * 32 + g * 4];
        const f32x4 mk1 = *(const f32x4*)&maskb[jc * 32 + 16 + g * 4];

        // softmax numerator (no max subtraction; logits are O(1), masked -> exp2(-1.5e9)=0)
#pragma unroll
        for (int it = 0; it < 4; ++it) {
            float p0[4], p1[4];
#pragma unroll
            for (int r = 0; r < 4; ++r) {
                p0[r] = exp2v(st[0][it][r] + pc0[it][r] + mk0[r]);
                p1[r] = exp2v(st[1][it][r] + pc1[it][r] + mk1[r]);
            }
#pragma unroll
            for (int r = 0; r < 4; ++r) lsum[it] += p0[r] + p1[r];
            ushort_t* base = p_w + (it * 16 + l16) * 40;
            *(uint2*)(base + g * 4)      = make_uint2(cvtpk(p0[0], p0[1]), cvtpk(p0[2], p0[3]));
            *(uint2*)(base + 16 + g * 4) = make_uint2(cvtpk(p1[0], p1[1]), cvtpk(p1[2], p1[3]));
        }
        // PV: O^T += mfma(V^T, P)
        __builtin_amdgcn_s_setprio(1);
#pragma unroll
        for (int it = 0; it < 4; ++it) {
            const bf16x8 bp = *(const bf16x8*)&p_w[(it * 16 + l16) * 40 + g * 8];
            oT[0][it] = mfma16(av[0], bp, oT[0][it]);
            oT[1][it] = mfma16(av[1], bp, oT[1][it]);
        }
        __builtin_amdgcn_s_setprio(0);

        // rotate double buffers
        if (jc < 7) {
#pragma unroll
            for (int jt = 0; jt < 2; ++jt) ak[jt] = akn[jt];
#pragma unroll
            for (int ct = 0; ct < 2; ++ct) av[ct] = avn[ct];
#pragma unroll
            for (int it = 0; it < 4; ++it) { pc0[it] = pn0[it]; pc1[it] = pn1[it]; }
        }
    }

    float inv[4];
#pragma unroll
    for (int it = 0; it < 4; ++it) {
        float s = lsum[it];
        s += __shfl_xor(s, 16, 64);
        s += __shfl_xor(s, 32, 64);
        inv[it] = rcpv(s);
    }

    __syncthreads();                      // all waves done reading vT
    ushort_t* oT_s = vT;                  // reuse as gated-output transpose buffer
#pragma unroll
    for (int ct = 0; ct < 2; ++ct)
#pragma unroll
        for (int it = 0; it < 4; ++it) {
            const int i = w * 64 + it * 16 + l16;
#pragma unroll
            for (int r = 0; r < 4; ++r) {
                const int c = ct * 16 + g * 4 + r;
                const float gate = bflo((uint_t)gT[c * 264 + i]);
                oT_s[c * 264 + i] = f2bf(oT[ct][it][r] * inv[it] * gate);
            }
        }
    __syncthreads();
    // coalesced bf16x2 store to ao[n*256+i][h*32+c]
    ushort_t* aob = ao + (size_t)n * 256 * 256 + h * 32;
#pragma unroll
    for (int iter = 0; iter < 16; ++iter) {
        const int flat = iter * 256 + t;
        const int i = flat >> 4, cp = flat & 15;
        const uint_t lo = oT_s[(2 * cp) * 264 + i];
        const uint_t hi = oT_s[(2 * cp + 1) * 264 + i];
        *(uint_t*)(aob + (size_t)i * 256 + 2 * cp) = lo | (hi << 16);
    }
}

// -------- K4: out = ao @ Wo + bo (MFMA), row-masked --------
__global__ __launch_bounds__(256, 2) void k_out(const ushort_t* __restrict__ ao,
                                                const ushort_t* __restrict__ woT,
                                                const float* __restrict__ bo,
                                                const int* __restrict__ msa_mask,
                                                float* __restrict__ out) {
    const int t = threadIdx.x;
    const int rb = blockIdx.x * 128;
    const int w = t >> 6, l = t & 63;
    const int l16 = l & 15, g = l >> 4;

#pragma unroll
    for (int ch = 0; ch < 2; ++ch) {
        f32x4 acc[2][8];
#pragma unroll
        for (int rt = 0; rt < 2; ++rt)
#pragma unroll
            for (int ct = 0; ct < 8; ++ct) acc[rt][ct] = (f32x4){0.f, 0.f, 0.f, 0.f};
#pragma unroll
        for (int ks = 0; ks < 8; ++ks) {
            bf16x8 a[2], b[8];
#pragma unroll
            for (int rt = 0; rt < 2; ++rt)
                a[rt] = *(const bf16x8*)(ao + (size_t)(rb + w * 32 + rt * 16 + l16) * 256 + ks * 32 + g * 8);
#pragma unroll
            for (int ct = 0; ct < 8; ++ct)
                b[ct] = *(const bf16x8*)(woT + (size_t)(ch * 128 + ct * 16 + l16) * 256 + ks * 32 + g * 8);
#pragma unroll
            for (int rt = 0; rt < 2; ++rt)
#pragma unroll
                for (int ct = 0; ct < 8; ++ct)
                    acc[rt][ct] = mfma16(a[rt], b[ct], acc[rt][ct]);
        }
#pragma unroll
        for (int rt = 0; rt < 2; ++rt)
#pragma unroll
            for (int ct = 0; ct < 8; ++ct) {
                const int c = ch * 128 + ct * 16 + l16;
                const float boc = bo[c];
#pragma unroll
                for (int r = 0; r < 4; ++r) {
                    const int row = rb + w * 32 + rt * 16 + g * 4 + r;
                    const float mk = msa_mask[row] ? 1.f : 0.f;
                    out[(size_t)row * 256 + c] = (acc[rt][ct][r] + boc) * mk;
                }
            }
    }
}

extern "C" void kernel_launch(void* const* d_in, const int* in_sizes, int n_in,
                              void* d_out, int out_size, void* d_ws, size_t ws_size,
                              hipStream_t stream) {
    const float* m       = (const float*)d_in[0];
    const float* z       = (const float*)d_in[1];
    const int* msa_mask  = (const int*)d_in[2];
    const float* ln_m_g  = (const float*)d_in[3];
    const float* ln_m_b  = (const float*)d_in[4];
    const float* ln_z_g  = (const float*)d_in[5];
    const float* ln_z_b  = (const float*)d_in[6];
    const float* Wq      = (const float*)d_in[7];
    const float* Wk      = (const float*)d_in[8];
    const float* Wv      = (const float*)d_in[9];
    const float* Wb      = (const float*)d_in[10];
    const float* Wg      = (const float*)d_in[11];
    const float* bg      = (const float*)d_in[12];
    const float* Wo      = (const float*)d_in[13];
    const float* bo      = (const float*)d_in[14];
    float* out           = (float*)d_out;

    char* ws = (char*)d_ws;
    ushort_t* mn  = (ushort_t*)(ws);                    // 33,554,432 B
    float*    pb  = (float*)(ws + 33554432);            //  2,097,152 B
    ushort_t* ao  = (ushort_t*)(ws + 35651584);         // 33,554,432 B
    ushort_t* wtT = (ushort_t*)(ws + 69206016);         //    524,288 B
    ushort_t* woT = (ushort_t*)(ws + 69730304);         //    131,072 B

    k_prep<<<256, 256, 0, stream>>>(Wq, Wk, Wv, Wg, Wo, wtT, woT);
    k_ln_m<<<16384, 256, 0, stream>>>(m, ln_m_g, ln_m_b, mn);
    k_pair_bias<<<16384, 256, 0, stream>>>(z, ln_z_g, ln_z_b, Wb, pb);
    k_attn<<<2048, 256, 0, stream>>>(mn, wtT, pb, msa_mask, bg, ao);
    k_out<<<512, 256, 0, stream>>>(ao, woT, bo, msa_mask, out);
}

// Round 10
// 265.067 us; speedup vs baseline: 1.1240x; 1.1240x over previous
//
#include <hip/hip_runtime.h>

typedef unsigned short ushort_t;
typedef unsigned int uint_t;
typedef __attribute__((ext_vector_type(8))) short bf16x8;
typedef __attribute__((ext_vector_type(4))) float f32x4;

#define EPSV 1e-5f
#define LOG2E 1.4426950408889634f
#define QSC (0.17677669529663687f * LOG2E)   // (1/sqrt(32)) * log2(e)

__device__ __forceinline__ float u2f(uint_t x) { return __builtin_bit_cast(float, x); }
__device__ __forceinline__ uint_t f2u(float x) { return __builtin_bit_cast(uint_t, x); }
__device__ __forceinline__ float bflo(uint_t u) { return u2f(u << 16); }
__device__ __forceinline__ float bfhi(uint_t u) { return u2f(u & 0xFFFF0000u); }
__device__ __forceinline__ ushort_t f2bf(float f) {
    uint_t x = f2u(f);
    x += 0x7FFFu + ((x >> 16) & 1u);   // RNE
    return (ushort_t)(x >> 16);
}
__device__ __forceinline__ uint_t cvtpk(float lo, float hi) {
    uint_t r;
    asm("v_cvt_pk_bf16_f32 %0, %1, %2" : "=v"(r) : "v"(lo), "v"(hi));
    return r;
}
__device__ __forceinline__ float exp2v(float x) {
    float r;
    asm("v_exp_f32 %0, %1" : "=v"(r) : "v"(x));
    return r;
}
__device__ __forceinline__ float rcpv(float x) {
    float r;
    asm("v_rcp_f32 %0, %1" : "=v"(r) : "v"(x));
    return r;
}
__device__ __forceinline__ f32x4 mfma16(bf16x8 a, bf16x8 b, f32x4 c) {
    return __builtin_amdgcn_mfma_f32_16x16x32_bf16(a, b, c, 0, 0, 0);
}
__device__ __forceinline__ float wsum(float v) {
#pragma unroll
    for (int m = 32; m >= 1; m >>= 1) v += __shfl_xor(v, m, 64);
    return v;
}

// -------- K0: pack transposed bf16 weights: wtT[h][c(128)][k(256)], woT[c][k],
//          and the pre-swizzled Wb B-fragment wbF[ks][lane][8] (heads 8..15 = 0) --------
__global__ __launch_bounds__(256) void k_prep(const float* __restrict__ Wq, const float* __restrict__ Wk,
                                              const float* __restrict__ Wv, const float* __restrict__ Wg,
                                              const float* __restrict__ Wo, const float* __restrict__ Wb,
                                              ushort_t* __restrict__ wtT, ushort_t* __restrict__ woT,
                                              ushort_t* __restrict__ wbF) {
    const int k = blockIdx.x, t = threadIdx.x;
    const int h = t >> 5, c = t & 31;
    wtT[(size_t)(h * 128 +   0 + c) * 256 + k] = f2bf(Wq[k * 256 + t]);
    wtT[(size_t)(h * 128 +  32 + c) * 256 + k] = f2bf(Wk[k * 256 + t]);
    wtT[(size_t)(h * 128 +  64 + c) * 256 + k] = f2bf(Wv[k * 256 + t]);
    wtT[(size_t)(h * 128 +  96 + c) * 256 + k] = f2bf(Wg[k * 256 + t]);
    woT[(size_t)t * 256 + k] = f2bf(Wo[k * 256 + t]);
    if (blockIdx.x == 0) {
        // B-fragment for mfma_16x16x32: lane l, elem j holds B[k = (l>>4)*8+j][n = l&15]
        const int ks = t >> 6, lane = t & 63;
        const int gq = (lane >> 4) & 3, l16w = lane & 15;
#pragma unroll
        for (int j = 0; j < 8; ++j)
            wbF[(ks * 64 + lane) * 8 + j] =
                (l16w < 8) ? f2bf(Wb[(ks * 32 + gq * 8 + j) * 8 + l16w]) : (ushort_t)0;
    }
}

// -------- K1: LayerNorm(m) -> mn (bf16) --------
__global__ __launch_bounds__(256) void k_ln_m(const float* __restrict__ m,
                                              const float* __restrict__ g,
                                              const float* __restrict__ b,
                                              ushort_t* __restrict__ mn) {
    const int lane = threadIdx.x & 63;
    const int row  = blockIdx.x * 4 + (threadIdx.x >> 6);
    const float4 x = *(const float4*)(m + (size_t)row * 256 + lane * 4);
    const float mu = wsum(x.x + x.y + x.z + x.w) * (1.f / 256.f);
    const float dx = x.x - mu, dy = x.y - mu, dz = x.z - mu, dw = x.w - mu;
    const float var = wsum(dx * dx + dy * dy + dz * dz + dw * dw) * (1.f / 256.f);
    const float rs = rsqrtf(var + EPSV);
    const float4 gg = *(const float4*)(g + lane * 4);
    const float4 bb = *(const float4*)(b + lane * 4);
    ushort4 o;
    o.x = f2bf(dx * rs * gg.x + bb.x);
    o.y = f2bf(dy * rs * gg.y + bb.y);
    o.z = f2bf(dz * rs * gg.z + bb.z);
    o.w = f2bf(dw * rs * gg.w + bb.w);
    *(ushort4*)(mn + (size_t)row * 256 + lane * 4) = o;
}

// -------- K2: LayerNorm(z) @ Wb -> pb[h][row] (f32, pre-scaled by log2e) --------
// MFMA rewrite: wave w owns 16 z-rows. Lane (l16,gq) loads row l16's elements
// in A-fragment order (cols ks*32+gq*8..+7); LN mean/var need only 2 shfls
// (xor16+xor32) for all 16 rows at once; 4 MFMAs vs 8 six-level wsums per row.
__global__ __launch_bounds__(256) void k_pair_bias(const float* __restrict__ z,
                                                   const float* __restrict__ gam,
                                                   const float* __restrict__ bet,
                                                   const ushort_t* __restrict__ wbF,
                                                   float* __restrict__ pb) {
    const int t = threadIdx.x;
    const int w = t >> 6, l = t & 63;
    const int l16 = l & 15, gq = l >> 4;
    const int row = blockIdx.x * 64 + w * 16 + l16;   // z-row this lane loads
    const float* zr = z + (size_t)row * 128;

    float v[32];
    float s1 = 0.f, s2 = 0.f;
#pragma unroll
    for (int ks = 0; ks < 4; ++ks) {
        const float4 a0 = *(const float4*)(zr + ks * 32 + gq * 8);
        const float4 a1 = *(const float4*)(zr + ks * 32 + gq * 8 + 4);
        v[ks * 8 + 0] = a0.x; v[ks * 8 + 1] = a0.y; v[ks * 8 + 2] = a0.z; v[ks * 8 + 3] = a0.w;
        v[ks * 8 + 4] = a1.x; v[ks * 8 + 5] = a1.y; v[ks * 8 + 6] = a1.z; v[ks * 8 + 7] = a1.w;
    }
#pragma unroll
    for (int j = 0; j < 32; ++j) { s1 += v[j]; s2 += v[j] * v[j]; }
    // row l16's 128 elems live on lanes {l16, 16+l16, 32+l16, 48+l16}
    s1 += __shfl_xor(s1, 16, 64); s1 += __shfl_xor(s1, 32, 64);
    s2 += __shfl_xor(s2, 16, 64); s2 += __shfl_xor(s2, 32, 64);
    const float mu = s1 * (1.f / 128.f);
    const float var = s2 * (1.f / 128.f) - mu * mu;
    const float rs = rsqrtf(var + EPSV);

    f32x4 acc = (f32x4){0.f, 0.f, 0.f, 0.f};
#pragma unroll
    for (int ks = 0; ks < 4; ++ks) {
        const float4 g0 = *(const float4*)(gam + ks * 32 + gq * 8);
        const float4 g1 = *(const float4*)(gam + ks * 32 + gq * 8 + 4);
        const float4 b0 = *(const float4*)(bet + ks * 32 + gq * 8);
        const float4 b1 = *(const float4*)(bet + ks * 32 + gq * 8 + 4);
        const float xn0 = (v[ks * 8 + 0] - mu) * rs * g0.x + b0.x;
        const float xn1 = (v[ks * 8 + 1] - mu) * rs * g0.y + b0.y;
        const float xn2 = (v[ks * 8 + 2] - mu) * rs * g0.z + b0.z;
        const float xn3 = (v[ks * 8 + 3] - mu) * rs * g0.w + b0.w;
        const float xn4 = (v[ks * 8 + 4] - mu) * rs * g1.x + b1.x;
        const float xn5 = (v[ks * 8 + 5] - mu) * rs * g1.y + b1.y;
        const float xn6 = (v[ks * 8 + 6] - mu) * rs * g1.z + b1.z;
        const float xn7 = (v[ks * 8 + 7] - mu) * rs * g1.w + b1.w;
        uint4 pk;
        pk.x = cvtpk(xn0, xn1); pk.y = cvtpk(xn2, xn3);
        pk.z = cvtpk(xn4, xn5); pk.w = cvtpk(xn6, xn7);
        const bf16x8 af = __builtin_bit_cast(bf16x8, pk);
        const bf16x8 bf_ = *(const bf16x8*)(wbF + (ks * 64 + l) * 8);
        acc = mfma16(af, bf_, acc);
    }
    // C-frag: lane (l16,gq) holds D[zrow-local = gq*4+r][head = l16]; heads 8..15 are zero-padded
    if (l16 < 8) {
        const int orow = blockIdx.x * 64 + w * 16 + gq * 4;
        f32x4 o;
        o[0] = acc[0] * LOG2E; o[1] = acc[1] * LOG2E;
        o[2] = acc[2] * LOG2E; o[3] = acc[3] * LOG2E;
        *(f32x4*)(pb + (size_t)l16 * 65536 + orow) = o;
    }
}

// -------- K3: MFMA fused QKVG projection + attention (no-max softmax) + gate --------
// FROZEN at the R8-passing configuration: 256 threads, __launch_bounds__(256,1),
// this LDS layout. Restructure attempts (R4 LDS re-arch, R6/R9 512-thread remap,
// R7 (256,2)) all produced NaN with no identifiable source-level bug — do not retry.
// Phase B is software-pipelined (depth-1 register double-buffering of K/V
// fragments and pair-bias loads) + setprio around MFMA clusters.
// blockIdx decode: n = bid & 255, h = bid >> 8 => all 8 heads of one n land on the
// same XCD (XCD = bid % 8 = n % 8), so mn[n] is fetched from HBM once, reused from L2.
__global__ __launch_bounds__(256, 1) void k_attn(const ushort_t* __restrict__ mn,
                                                 const ushort_t* __restrict__ wtT,
                                                 const float* __restrict__ pb,
                                                 const int* __restrict__ msa_mask,
                                                 const float* __restrict__ bg,
                                                 ushort_t* __restrict__ ao) {
    __shared__ ushort_t k_s[256 * 40];   // [j][c], 80B rows
    __shared__ ushort_t qp_s[256 * 40];  // Phase A: q[i][c]; Phase B (after q->regs): P[w][i64][j32] per wave
    __shared__ ushort_t vT[32 * 264];    // [c][j], later reused as gated-output transpose
    __shared__ ushort_t gT[32 * 264];    // [c][i], holds sigmoid gate (bf16)
    __shared__ float maskb[256];

    const int t = threadIdx.x;
    const int n = blockIdx.x & 255, h = blockIdx.x >> 8;
    const int w = t >> 6, l = t & 63;
    const int l16 = l & 15, g = l >> 4;

    maskb[t] = msa_mask[n * 256 + t] ? 0.f : -1.5e9f;
    const float bg0 = bg[h * 32 + l16];
    const float bg1 = bg[h * 32 + 16 + l16];

    const ushort_t* mb = mn + (size_t)n * 65536;
    const ushort_t* wb = wtT + (size_t)h * 128 * 256;

    // ---- Phase A: qkvg[i][c] = mn[i][:] @ W[:,c] via MFMA ----
#pragma unroll
    for (int chalf = 0; chalf < 2; ++chalf) {
        f32x4 acc[4][4];
#pragma unroll
        for (int rt = 0; rt < 4; ++rt)
#pragma unroll
            for (int ct = 0; ct < 4; ++ct) acc[rt][ct] = (f32x4){0.f, 0.f, 0.f, 0.f};

#pragma unroll
        for (int ks = 0; ks < 8; ++ks) {
            bf16x8 a[4], b[4];
#pragma unroll
            for (int rt = 0; rt < 4; ++rt)
                a[rt] = *(const bf16x8*)(mb + (size_t)(w * 64 + rt * 16 + l16) * 256 + ks * 32 + g * 8);
#pragma unroll
            for (int ct = 0; ct < 4; ++ct)
                b[ct] = *(const bf16x8*)(wb + (size_t)(chalf * 64 + ct * 16 + l16) * 256 + ks * 32 + g * 8);
#pragma unroll
            for (int rt = 0; rt < 4; ++rt)
#pragma unroll
                for (int ct = 0; ct < 4; ++ct)
                    acc[rt][ct] = mfma16(a[rt], b[ct], acc[rt][ct]);
        }
        // epilogue: C-frag lane holds [row = g*4+r][col = l16]
#pragma unroll
        for (int ct = 0; ct < 4; ++ct) {
            const int mat = chalf * 2 + (ct >> 1);       // 0 q, 1 k, 2 v, 3 g
            const int cc = (ct & 1) * 16 + l16;
#pragma unroll
            for (int rt = 0; rt < 4; ++rt) {
                const int i0 = w * 64 + rt * 16 + g * 4;
                const f32x4 v = acc[rt][ct];
                if (mat == 0) {          // q: fold SCALE*log2e
#pragma unroll
                    for (int r = 0; r < 4; ++r) qp_s[(i0 + r) * 40 + cc] = f2bf(v[r] * QSC);
                } else if (mat == 1) {   // k
#pragma unroll
                    for (int r = 0; r < 4; ++r) k_s[(i0 + r) * 40 + cc] = f2bf(v[r]);
                } else if (mat == 2) {   // v -> transposed
                    const uint_t lo = cvtpk(v[0], v[1]);
                    const uint_t hi = cvtpk(v[2], v[3]);
                    *(uint2*)(vT + cc * 264 + i0) = make_uint2(lo, hi);
                } else {                 // g -> sigmoid gate, transposed
                    const float bgc = (ct & 1) ? bg1 : bg0;
                    float gt[4];
#pragma unroll
                    for (int r = 0; r < 4; ++r)
                        gt[r] = rcpv(1.f + exp2v(-(v[r] + bgc) * LOG2E));
                    const uint_t lo = cvtpk(gt[0], gt[1]);
                    const uint_t hi = cvtpk(gt[2], gt[3]);
                    *(uint2*)(gT + cc * 264 + i0) = make_uint2(lo, hi);
                }
            }
        }
    }
    __syncthreads();

    // ---- Phase B: attention. Wave w owns rows i in [w*64, w*64+64). ----
    // Hoist q fragments to registers, then reuse qp_s rows [w*64, w*64+64) as the
    // wave-private P buffer (no barrier needed: same-wave producer/consumer).
    bf16x8 bq[4];
#pragma unroll
    for (int it = 0; it < 4; ++it)
        bq[it] = *(const bf16x8*)&qp_s[(w * 64 + it * 16 + l16) * 40 + g * 8];
    ushort_t* p_w = qp_s + w * 64 * 40;

    const float* pbh = pb + (size_t)h * 65536;
    f32x4 oT[2][4];
#pragma unroll
    for (int ct = 0; ct < 2; ++ct)
#pragma unroll
        for (int it = 0; it < 4; ++it) oT[ct][it] = (f32x4){0.f, 0.f, 0.f, 0.f};
    float lsum[4] = {0.f, 0.f, 0.f, 0.f};

    // pipeline prologue: K/V fragments + pair-bias for jc=0
    bf16x8 ak[2], av[2];
    f32x4 pc0[4], pc1[4];
#pragma unroll
    for (int jt = 0; jt < 2; ++jt)
        ak[jt] = *(const bf16x8*)&k_s[(jt * 16 + l16) * 40 + g * 8];
#pragma unroll
    for (int ct = 0; ct < 2; ++ct)
        av[ct] = *(const bf16x8*)&vT[(ct * 16 + l16) * 264 + g * 8];
#pragma unroll
    for (int it = 0; it < 4; ++it) {
        const int i = w * 64 + it * 16 + l16;
        pc0[it] = *(const f32x4*)(pbh + (size_t)i * 256 + g * 4);
        pc1[it] = *(const f32x4*)(pbh + (size_t)i * 256 + 16 + g * 4);
    }

    for (int jc = 0; jc < 8; ++jc) {
        // prefetch next iteration's K/V fragments + pair-bias (latency hides
        // under this iteration's S-MFMA + softmax + PV)
        bf16x8 akn[2], avn[2];
        f32x4 pn0[4], pn1[4];
        if (jc < 7) {
            const int j0 = (jc + 1) * 32;
#pragma unroll
            for (int jt = 0; jt < 2; ++jt)
                akn[jt] = *(const bf16x8*)&k_s[(j0 + jt * 16 + l16) * 40 + g * 8];
#pragma unroll
            for (int ct = 0; ct < 2; ++ct)
                avn[ct] = *(const bf16x8*)&vT[(ct * 16 + l16) * 264 + j0 + g * 8];
#pragma unroll
            for (int it = 0; it < 4; ++it) {
                const int i = w * 64 + it * 16 + l16;
                pn0[it] = *(const f32x4*)(pbh + (size_t)i * 256 + j0 + g * 4);
                pn1[it] = *(const f32x4*)(pbh + (size_t)i * 256 + j0 + 16 + g * 4);
            }
        }

        // S^T = mfma(K, Q): lane holds S[j = jc*32 + jt*16 + g*4 + r][i = it*16 + l16]
        f32x4 st[2][4];
        __builtin_amdgcn_s_setprio(1);
#pragma unroll
        for (int jt = 0; jt < 2; ++jt)
#pragma unroll
            for (int it = 0; it < 4; ++it)
                st[jt][it] = mfma16(ak[jt], bq[it], (f32x4){0.f, 0.f, 0.f, 0.f});
        __builtin_amdgcn_s_setprio(0);

        const f32x4 mk0 = *(const f32x4*)&maskb[jc * 32 + g * 4];
        const f32x4 mk1 = *(const f32x4*)&maskb[jc * 32 + 16 + g * 4];

        // softmax numerator (no max subtraction; logits are O(1), masked -> exp2(-1.5e9)=0)
#pragma unroll
        for (int it = 0; it < 4; ++it) {
            float p0[4], p1[4];
#pragma unroll
            for (int r = 0; r < 4; ++r) {
                p0[r] = exp2v(st[0][it][r] + pc0[it][r] + mk0[r]);
                p1[r] = exp2v(st[1][it][r] + pc1[it][r] + mk1[r]);
            }
#pragma unroll
            for (int r = 0; r < 4; ++r) lsum[it] += p0[r] + p1[r];
            ushort_t* base = p_w + (it * 16 + l16) * 40;
            *(uint2*)(base + g * 4)      = make_uint2(cvtpk(p0[0], p0[1]), cvtpk(p0[2], p0[3]));
            *(uint2*)(base + 16 + g * 4) = make_uint2(cvtpk(p1[0], p1[1]), cvtpk(p1[2], p1[3]));
        }
        // PV: O^T += mfma(V^T, P)
        __builtin_amdgcn_s_setprio(1);
#pragma unroll
        for (int it = 0; it < 4; ++it) {
            const bf16x8 bp = *(const bf16x8*)&p_w[(it * 16 + l16) * 40 + g * 8];
            oT[0][it] = mfma16(av[0], bp, oT[0][it]);
            oT[1][it] = mfma16(av[1], bp, oT[1][it]);
        }
        __builtin_amdgcn_s_setprio(0);

        // rotate double buffers
        if (jc < 7) {
#pragma unroll
            for (int jt = 0; jt < 2; ++jt) ak[jt] = akn[jt];
#pragma unroll
            for (int ct = 0; ct < 2; ++ct) av[ct] = avn[ct];
#pragma unroll
            for (int it = 0; it < 4; ++it) { pc0[it] = pn0[it]; pc1[it] = pn1[it]; }
        }
    }

    float inv[4];
#pragma unroll
    for (int it = 0; it < 4; ++it) {
        float s = lsum[it];
        s += __shfl_xor(s, 16, 64);
        s += __shfl_xor(s, 32, 64);
        inv[it] = rcpv(s);
    }

    __syncthreads();                      // all waves done reading vT
    ushort_t* oT_s = vT;                  // reuse as gated-output transpose buffer
#pragma unroll
    for (int ct = 0; ct < 2; ++ct)
#pragma unroll
        for (int it = 0; it < 4; ++it) {
            const int i = w * 64 + it * 16 + l16;
#pragma unroll
            for (int r = 0; r < 4; ++r) {
                const int c = ct * 16 + g * 4 + r;
                const float gate = bflo((uint_t)gT[c * 264 + i]);
                oT_s[c * 264 + i] = f2bf(oT[ct][it][r] * inv[it] * gate);
            }
        }
    __syncthreads();
    // coalesced bf16x2 store to ao[n*256+i][h*32+c]
    ushort_t* aob = ao + (size_t)n * 256 * 256 + h * 32;
#pragma unroll
    for (int iter = 0; iter < 16; ++iter) {
        const int flat = iter * 256 + t;
        const int i = flat >> 4, cp = flat & 15;
        const uint_t lo = oT_s[(2 * cp) * 264 + i];
        const uint_t hi = oT_s[(2 * cp + 1) * 264 + i];
        *(uint_t*)(aob + (size_t)i * 256 + 2 * cp) = lo | (hi << 16);
    }
}

// -------- K4: out = ao @ Wo + bo (MFMA), row-masked --------
__global__ __launch_bounds__(256, 2) void k_out(const ushort_t* __restrict__ ao,
                                                const ushort_t* __restrict__ woT,
                                                const float* __restrict__ bo,
                                                const int* __restrict__ msa_mask,
                                                float* __restrict__ out) {
    const int t = threadIdx.x;
    const int rb = blockIdx.x * 128;
    const int w = t >> 6, l = t & 63;
    const int l16 = l & 15, g = l >> 4;

#pragma unroll
    for (int ch = 0; ch < 2; ++ch) {
        f32x4 acc[2][8];
#pragma unroll
        for (int rt = 0; rt < 2; ++rt)
#pragma unroll
            for (int ct = 0; ct < 8; ++ct) acc[rt][ct] = (f32x4){0.f, 0.f, 0.f, 0.f};
#pragma unroll
        for (int ks = 0; ks < 8; ++ks) {
            bf16x8 a[2], b[8];
#pragma unroll
            for (int rt = 0; rt < 2; ++rt)
                a[rt] = *(const bf16x8*)(ao + (size_t)(rb + w * 32 + rt * 16 + l16) * 256 + ks * 32 + g * 8);
#pragma unroll
            for (int ct = 0; ct < 8; ++ct)
                b[ct] = *(const bf16x8*)(woT + (size_t)(ch * 128 + ct * 16 + l16) * 256 + ks * 32 + g * 8);
#pragma unroll
            for (int rt = 0; rt < 2; ++rt)
#pragma unroll
                for (int ct = 0; ct < 8; ++ct)
                    acc[rt][ct] = mfma16(a[rt], b[ct], acc[rt][ct]);
        }
#pragma unroll
        for (int rt = 0; rt < 2; ++rt)
#pragma unroll
            for (int ct = 0; ct < 8; ++ct) {
                const int c = ch * 128 + ct * 16 + l16;
                const float boc = bo[c];
#pragma unroll
                for (int r = 0; r < 4; ++r) {
                    const int row = rb + w * 32 + rt * 16 + g * 4 + r;
                    const float mk = msa_mask[row] ? 1.f : 0.f;
                    out[(size_t)row * 256 + c] = (acc[rt][ct][r] + boc) * mk;
                }
            }
    }
}

extern "C" void kernel_launch(void* const* d_in, const int* in_sizes, int n_in,
                              void* d_out, int out_size, void* d_ws, size_t ws_size,
                              hipStream_t stream) {
    const float* m       = (const float*)d_in[0];
    const float* z       = (const float*)d_in[1];
    const int* msa_mask  = (const int*)d_in[2];
    const float* ln_m_g  = (const float*)d_in[3];
    const float* ln_m_b  = (const float*)d_in[4];
    const float* ln_z_g  = (const float*)d_in[5];
    const float* ln_z_b  = (const float*)d_in[6];
    const float* Wq      = (const float*)d_in[7];
    const float* Wk      = (const float*)d_in[8];
    const float* Wv      = (const float*)d_in[9];
    const float* Wb      = (const float*)d_in[10];
    const float* Wg      = (const float*)d_in[11];
    const float* bg      = (const float*)d_in[12];
    const float* Wo      = (const float*)d_in[13];
    const float* bo      = (const float*)d_in[14];
    float* out           = (float*)d_out;

    char* ws = (char*)d_ws;
    ushort_t* mn  = (ushort_t*)(ws);                    // 33,554,432 B
    float*    pb  = (float*)(ws + 33554432);            //  2,097,152 B
    ushort_t* ao  = (ushort_t*)(ws + 35651584);         // 33,554,432 B
    ushort_t* wtT = (ushort_t*)(ws + 69206016);         //    524,288 B
    ushort_t* woT = (ushort_t*)(ws + 69730304);         //    131,072 B
    ushort_t* wbF = (ushort_t*)(ws + 69861376);         //      4,096 B

    k_prep<<<256, 256, 0, stream>>>(Wq, Wk, Wv, Wg, Wo, Wb, wtT, woT, wbF);
    k_ln_m<<<16384, 256, 0, stream>>>(m, ln_m_g, ln_m_b, mn);
    k_pair_bias<<<1024, 256, 0, stream>>>(z, ln_z_g, ln_z_b, wbF, pb);
    k_attn<<<2048, 256, 0, stream>>>(mn, wtT, pb, msa_mask, bg, ao);
    k_out<<<512, 256, 0, stream>>>(ao, woT, bo, msa_mask, out);
}

// Round 11
// 262.517 us; speedup vs baseline: 1.1349x; 1.0097x over previous
//
#include <hip/hip_runtime.h>

typedef unsigned short ushort_t;
typedef unsigned int uint_t;
typedef __attribute__((ext_vector_type(8))) short bf16x8;
typedef __attribute__((ext_vector_type(4))) float f32x4;

#define EPSV 1e-5f
#define LOG2E 1.4426950408889634f
#define QSC (0.17677669529663687f * LOG2E)   // (1/sqrt(32)) * log2(e)

__device__ __forceinline__ float u2f(uint_t x) { return __builtin_bit_cast(float, x); }
__device__ __forceinline__ uint_t f2u(float x) { return __builtin_bit_cast(uint_t, x); }
__device__ __forceinline__ float bflo(uint_t u) { return u2f(u << 16); }
__device__ __forceinline__ float bfhi(uint_t u) { return u2f(u & 0xFFFF0000u); }
__device__ __forceinline__ ushort_t f2bf(float f) {
    uint_t x = f2u(f);
    x += 0x7FFFu + ((x >> 16) & 1u);   // RNE
    return (ushort_t)(x >> 16);
}
__device__ __forceinline__ uint_t cvtpk(float lo, float hi) {
    uint_t r;
    asm("v_cvt_pk_bf16_f32 %0, %1, %2" : "=v"(r) : "v"(lo), "v"(hi));
    return r;
}
__device__ __forceinline__ float exp2v(float x) {
    float r;
    asm("v_exp_f32 %0, %1" : "=v"(r) : "v"(x));
    return r;
}
__device__ __forceinline__ float rcpv(float x) {
    float r;
    asm("v_rcp_f32 %0, %1" : "=v"(r) : "v"(x));
    return r;
}
__device__ __forceinline__ f32x4 mfma16(bf16x8 a, bf16x8 b, f32x4 c) {
    return __builtin_amdgcn_mfma_f32_16x16x32_bf16(a, b, c, 0, 0, 0);
}
__device__ __forceinline__ float wsum(float v) {
#pragma unroll
    for (int m = 32; m >= 1; m >>= 1) v += __shfl_xor(v, m, 64);
    return v;
}

// -------- K_pre: fused {LayerNorm(m) | LayerNorm(z)@Wb | weight transpose} --------
// blockIdx dispatch: [0,16384) -> ln_m (4 m-rows each); [16384,17408) -> pair_bias
// (64 z-rows each, Wb staged to LDS per block); [17408,17664) -> weight prep.
// The three roles are data-independent, so one kernel lets the scheduler pack
// prep's scatter stores and pair_bias under ln_m's memory streams (saves 2
// launch gaps + tail under-utilization).
#define NB_LN 16384
#define NB_PB 1024
__global__ __launch_bounds__(256) void k_pre(const float* __restrict__ m,
                                             const float* __restrict__ ln_m_g,
                                             const float* __restrict__ ln_m_b,
                                             const float* __restrict__ z,
                                             const float* __restrict__ ln_z_g,
                                             const float* __restrict__ ln_z_b,
                                             const float* __restrict__ Wb,
                                             const float* __restrict__ Wq, const float* __restrict__ Wk,
                                             const float* __restrict__ Wv, const float* __restrict__ Wg,
                                             const float* __restrict__ Wo,
                                             ushort_t* __restrict__ mn,
                                             float* __restrict__ pb,
                                             ushort_t* __restrict__ wtT, ushort_t* __restrict__ woT) {
    __shared__ float wb_lds[1024];
    const int bid = blockIdx.x, t = threadIdx.x;

    if (bid < NB_LN) {
        // ---- LayerNorm(m) -> mn (bf16) ----
        const int lane = t & 63;
        const int row  = bid * 4 + (t >> 6);
        const float4 x = *(const float4*)(m + (size_t)row * 256 + lane * 4);
        const float mu = wsum(x.x + x.y + x.z + x.w) * (1.f / 256.f);
        const float dx = x.x - mu, dy = x.y - mu, dz = x.z - mu, dw = x.w - mu;
        const float var = wsum(dx * dx + dy * dy + dz * dz + dw * dw) * (1.f / 256.f);
        const float rs = rsqrtf(var + EPSV);
        const float4 gg = *(const float4*)(ln_m_g + lane * 4);
        const float4 bb = *(const float4*)(ln_m_b + lane * 4);
        ushort4 o;
        o.x = f2bf(dx * rs * gg.x + bb.x);
        o.y = f2bf(dy * rs * gg.y + bb.y);
        o.z = f2bf(dz * rs * gg.z + bb.z);
        o.w = f2bf(dw * rs * gg.w + bb.w);
        *(ushort4*)(mn + (size_t)row * 256 + lane * 4) = o;
    } else if (bid < NB_LN + NB_PB) {
        // ---- LayerNorm(z) @ Wb -> pb[h][row] (f32, pre-scaled by log2e) ----
        // Wave w owns 16 z-rows; lane (l16,gq) loads row l16's elems in A-frag order;
        // LN mean/var via 2 shfls; 4 MFMAs with an in-block-built Wb B-fragment.
        const int pbid = bid - NB_LN;
        const int w = t >> 6, l = t & 63;
        const int l16 = l & 15, gq = l >> 4;
        // stage Wb (128x8 f32 = 4KB) to LDS
        *(float4*)&wb_lds[t * 4] = *(const float4*)(Wb + t * 4);
        __syncthreads();

        const int row = pbid * 64 + w * 16 + l16;
        const float* zr = z + (size_t)row * 128;
        float v[32];
        float s1 = 0.f, s2 = 0.f;
#pragma unroll
        for (int ks = 0; ks < 4; ++ks) {
            const float4 a0 = *(const float4*)(zr + ks * 32 + gq * 8);
            const float4 a1 = *(const float4*)(zr + ks * 32 + gq * 8 + 4);
            v[ks * 8 + 0] = a0.x; v[ks * 8 + 1] = a0.y; v[ks * 8 + 2] = a0.z; v[ks * 8 + 3] = a0.w;
            v[ks * 8 + 4] = a1.x; v[ks * 8 + 5] = a1.y; v[ks * 8 + 6] = a1.z; v[ks * 8 + 7] = a1.w;
        }
#pragma unroll
        for (int j = 0; j < 32; ++j) { s1 += v[j]; s2 += v[j] * v[j]; }
        s1 += __shfl_xor(s1, 16, 64); s1 += __shfl_xor(s1, 32, 64);
        s2 += __shfl_xor(s2, 16, 64); s2 += __shfl_xor(s2, 32, 64);
        const float mu = s1 * (1.f / 128.f);
        const float var = s2 * (1.f / 128.f) - mu * mu;
        const float rs = rsqrtf(var + EPSV);

        f32x4 acc = (f32x4){0.f, 0.f, 0.f, 0.f};
#pragma unroll
        for (int ks = 0; ks < 4; ++ks) {
            const float4 g0 = *(const float4*)(ln_z_g + ks * 32 + gq * 8);
            const float4 g1 = *(const float4*)(ln_z_g + ks * 32 + gq * 8 + 4);
            const float4 b0 = *(const float4*)(ln_z_b + ks * 32 + gq * 8);
            const float4 b1 = *(const float4*)(ln_z_b + ks * 32 + gq * 8 + 4);
            const float xn0 = (v[ks * 8 + 0] - mu) * rs * g0.x + b0.x;
            const float xn1 = (v[ks * 8 + 1] - mu) * rs * g0.y + b0.y;
            const float xn2 = (v[ks * 8 + 2] - mu) * rs * g0.z + b0.z;
            const float xn3 = (v[ks * 8 + 3] - mu) * rs * g0.w + b0.w;
            const float xn4 = (v[ks * 8 + 4] - mu) * rs * g1.x + b1.x;
            const float xn5 = (v[ks * 8 + 5] - mu) * rs * g1.y + b1.y;
            const float xn6 = (v[ks * 8 + 6] - mu) * rs * g1.z + b1.z;
            const float xn7 = (v[ks * 8 + 7] - mu) * rs * g1.w + b1.w;
            uint4 pk;
            pk.x = cvtpk(xn0, xn1); pk.y = cvtpk(xn2, xn3);
            pk.z = cvtpk(xn4, xn5); pk.w = cvtpk(xn6, xn7);
            const bf16x8 af = __builtin_bit_cast(bf16x8, pk);
            // B-frag: lane l, elem j holds Wb[k = ks*32 + gq*8 + j][head = l16] (heads 8..15 -> 0)
            ushort_t wf[8];
#pragma unroll
            for (int j = 0; j < 8; ++j)
                wf[j] = (l16 < 8) ? f2bf(wb_lds[(ks * 32 + gq * 8 + j) * 8 + l16]) : (ushort_t)0;
            const bf16x8 bf_ = *(const bf16x8*)wf;
            acc = mfma16(af, bf_, acc);
        }
        if (l16 < 8) {
            const int orow = pbid * 64 + w * 16 + gq * 4;
            f32x4 o;
            o[0] = acc[0] * LOG2E; o[1] = acc[1] * LOG2E;
            o[2] = acc[2] * LOG2E; o[3] = acc[3] * LOG2E;
            *(f32x4*)(pb + (size_t)l16 * 65536 + orow) = o;
        }
    } else {
        // ---- weight transpose: wtT[h][c(128)][k(256)], woT[c][k] ----
        const int k = bid - (NB_LN + NB_PB);
        const int h = t >> 5, c = t & 31;
        wtT[(size_t)(h * 128 +   0 + c) * 256 + k] = f2bf(Wq[k * 256 + t]);
        wtT[(size_t)(h * 128 +  32 + c) * 256 + k] = f2bf(Wk[k * 256 + t]);
        wtT[(size_t)(h * 128 +  64 + c) * 256 + k] = f2bf(Wv[k * 256 + t]);
        wtT[(size_t)(h * 128 +  96 + c) * 256 + k] = f2bf(Wg[k * 256 + t]);
        woT[(size_t)t * 256 + k] = f2bf(Wo[k * 256 + t]);
    }
}

// -------- K3: MFMA fused QKVG projection + attention (no-max softmax) + gate --------
// FROZEN at the R8-passing configuration: 256 threads, __launch_bounds__(256,1),
// this LDS layout. Restructure attempts (R4 LDS re-arch, R6/R9 512-thread remap,
// R7 (256,2)) all produced NaN with no identifiable source-level bug — do not retry.
// Phase B is software-pipelined (depth-1 register double-buffering of K/V
// fragments and pair-bias loads) + setprio around MFMA clusters.
// blockIdx decode: n = bid & 255, h = bid >> 8 => all 8 heads of one n land on the
// same XCD (XCD = bid % 8 = n % 8), so mn[n] is fetched from HBM once, reused from L2.
__global__ __launch_bounds__(256, 1) void k_attn(const ushort_t* __restrict__ mn,
                                                 const ushort_t* __restrict__ wtT,
                                                 const float* __restrict__ pb,
                                                 const int* __restrict__ msa_mask,
                                                 const float* __restrict__ bg,
                                                 ushort_t* __restrict__ ao) {
    __shared__ ushort_t k_s[256 * 40];   // [j][c], 80B rows
    __shared__ ushort_t qp_s[256 * 40];  // Phase A: q[i][c]; Phase B (after q->regs): P[w][i64][j32] per wave
    __shared__ ushort_t vT[32 * 264];    // [c][j], later reused as gated-output transpose
    __shared__ ushort_t gT[32 * 264];    // [c][i], holds sigmoid gate (bf16)
    __shared__ float maskb[256];

    const int t = threadIdx.x;
    const int n = blockIdx.x & 255, h = blockIdx.x >> 8;
    const int w = t >> 6, l = t & 63;
    const int l16 = l & 15, g = l >> 4;

    maskb[t] = msa_mask[n * 256 + t] ? 0.f : -1.5e9f;
    const float bg0 = bg[h * 32 + l16];
    const float bg1 = bg[h * 32 + 16 + l16];

    const ushort_t* mb = mn + (size_t)n * 65536;
    const ushort_t* wb = wtT + (size_t)h * 128 * 256;

    // ---- Phase A: qkvg[i][c] = mn[i][:] @ W[:,c] via MFMA ----
#pragma unroll
    for (int chalf = 0; chalf < 2; ++chalf) {
        f32x4 acc[4][4];
#pragma unroll
        for (int rt = 0; rt < 4; ++rt)
#pragma unroll
            for (int ct = 0; ct < 4; ++ct) acc[rt][ct] = (f32x4){0.f, 0.f, 0.f, 0.f};

#pragma unroll
        for (int ks = 0; ks < 8; ++ks) {
            bf16x8 a[4], b[4];
#pragma unroll
            for (int rt = 0; rt < 4; ++rt)
                a[rt] = *(const bf16x8*)(mb + (size_t)(w * 64 + rt * 16 + l16) * 256 + ks * 32 + g * 8);
#pragma unroll
            for (int ct = 0; ct < 4; ++ct)
                b[ct] = *(const bf16x8*)(wb + (size_t)(chalf * 64 + ct * 16 + l16) * 256 + ks * 32 + g * 8);
#pragma unroll
            for (int rt = 0; rt < 4; ++rt)
#pragma unroll
                for (int ct = 0; ct < 4; ++ct)
                    acc[rt][ct] = mfma16(a[rt], b[ct], acc[rt][ct]);
        }
        // epilogue: C-frag lane holds [row = g*4+r][col = l16]
#pragma unroll
        for (int ct = 0; ct < 4; ++ct) {
            const int mat = chalf * 2 + (ct >> 1);       // 0 q, 1 k, 2 v, 3 g
            const int cc = (ct & 1) * 16 + l16;
#pragma unroll
            for (int rt = 0; rt < 4; ++rt) {
                const int i0 = w * 64 + rt * 16 + g * 4;
                const f32x4 v = acc[rt][ct];
                if (mat == 0) {          // q: fold SCALE*log2e
#pragma unroll
                    for (int r = 0; r < 4; ++r) qp_s[(i0 + r) * 40 + cc] = f2bf(v[r] * QSC);
                } else if (mat == 1) {   // k
#pragma unroll
                    for (int r = 0; r < 4; ++r) k_s[(i0 + r) * 40 + cc] = f2bf(v[r]);
                } else if (mat == 2) {   // v -> transposed
                    const uint_t lo = cvtpk(v[0], v[1]);
                    const uint_t hi = cvtpk(v[2], v[3]);
                    *(uint2*)(vT + cc * 264 + i0) = make_uint2(lo, hi);
                } else {                 // g -> sigmoid gate, transposed
                    const float bgc = (ct & 1) ? bg1 : bg0;
                    float gt[4];
#pragma unroll
                    for (int r = 0; r < 4; ++r)
                        gt[r] = rcpv(1.f + exp2v(-(v[r] + bgc) * LOG2E));
                    const uint_t lo = cvtpk(gt[0], gt[1]);
                    const uint_t hi = cvtpk(gt[2], gt[3]);
                    *(uint2*)(gT + cc * 264 + i0) = make_uint2(lo, hi);
                }
            }
        }
    }
    __syncthreads();

    // ---- Phase B: attention. Wave w owns rows i in [w*64, w*64+64). ----
    // Hoist q fragments to registers, then reuse qp_s rows [w*64, w*64+64) as the
    // wave-private P buffer (no barrier needed: same-wave producer/consumer).
    bf16x8 bq[4];
#pragma unroll
    for (int it = 0; it < 4; ++it)
        bq[it] = *(const bf16x8*)&qp_s[(w * 64 + it * 16 + l16) * 40 + g * 8];
    ushort_t* p_w = qp_s + w * 64 * 40;

    const float* pbh = pb + (size_t)h * 65536;
    f32x4 oT[2][4];
#pragma unroll
    for (int ct = 0; ct < 2; ++ct)
#pragma unroll
        for (int it = 0; it < 4; ++it) oT[ct][it] = (f32x4){0.f, 0.f, 0.f, 0.f};
    float lsum[4] = {0.f, 0.f, 0.f, 0.f};

    // pipeline prologue: K/V fragments + pair-bias for jc=0
    bf16x8 ak[2], av[2];
    f32x4 pc0[4], pc1[4];
#pragma unroll
    for (int jt = 0; jt < 2; ++jt)
        ak[jt] = *(const bf16x8*)&k_s[(jt * 16 + l16) * 40 + g * 8];
#pragma unroll
    for (int ct = 0; ct < 2; ++ct)
        av[ct] = *(const bf16x8*)&vT[(ct * 16 + l16) * 264 + g * 8];
#pragma unroll
    for (int it = 0; it < 4; ++it) {
        const int i = w * 64 + it * 16 + l16;
        pc0[it] = *(const f32x4*)(pbh + (size_t)i * 256 + g * 4);
        pc1[it] = *(const f32x4*)(pbh + (size_t)i * 256 + 16 + g * 4);
    }

    for (int jc = 0; jc < 8; ++jc) {
        // prefetch next iteration's K/V fragments + pair-bias (latency hides
        // under this iteration's S-MFMA + softmax + PV)
        bf16x8 akn[2], avn[2];
        f32x4 pn0[4], pn1[4];
        if (jc < 7) {
            const int j0 = (jc + 1) * 32;
#pragma unroll
            for (int jt = 0; jt < 2; ++jt)
                akn[jt] = *(const bf16x8*)&k_s[(j0 + jt * 16 + l16) * 40 + g * 8];
#pragma unroll
            for (int ct = 0; ct < 2; ++ct)
                avn[ct] = *(const bf16x8*)&vT[(ct * 16 + l16) * 264 + j0 + g * 8];
#pragma unroll
            for (int it = 0; it < 4; ++it) {
                const int i = w * 64 + it * 16 + l16;
                pn0[it] = *(const f32x4*)(pbh + (size_t)i * 256 + j0 + g * 4);
                pn1[it] = *(const f32x4*)(pbh + (size_t)i * 256 + j0 + 16 + g * 4);
            }
        }

        // S^T = mfma(K, Q): lane holds S[j = jc*32 + jt*16 + g*4 + r][i = it*16 + l16]
        f32x4 st[2][4];
        __builtin_amdgcn_s_setprio(1);
#pragma unroll
        for (int jt = 0; jt < 2; ++jt)
#pragma unroll
            for (int it = 0; it < 4; ++it)
                st[jt][it] = mfma16(ak[jt], bq[it], (f32x4){0.f, 0.f, 0.f, 0.f});
        __builtin_amdgcn_s_setprio(0);

        const f32x4 mk0 = *(const f32x4*)&maskb[jc * 32 + g * 4];
        const f32x4 mk1 = *(const f32x4*)&maskb[jc * 32 + 16 + g * 4];

        // softmax numerator (no max subtraction; logits are O(1), masked -> exp2(-1.5e9)=0)
#pragma unroll
        for (int it = 0; it < 4; ++it) {
            float p0[4], p1[4];
#pragma unroll
            for (int r = 0; r < 4; ++r) {
                p0[r] = exp2v(st[0][it][r] + pc0[it][r] + mk0[r]);
                p1[r] = exp2v(st[1][it][r] + pc1[it][r] + mk1[r]);
            }
#pragma unroll
            for (int r = 0; r < 4; ++r) lsum[it] += p0[r] + p1[r];
            ushort_t* base = p_w + (it * 16 + l16) * 40;
            *(uint2*)(base + g * 4)      = make_uint2(cvtpk(p0[0], p0[1]), cvtpk(p0[2], p0[3]));
            *(uint2*)(base + 16 + g * 4) = make_uint2(cvtpk(p1[0], p1[1]), cvtpk(p1[2], p1[3]));
        }
        // PV: O^T += mfma(V^T, P)
        __builtin_amdgcn_s_setprio(1);
#pragma unroll
        for (int it = 0; it < 4; ++it) {
            const bf16x8 bp = *(const bf16x8*)&p_w[(it * 16 + l16) * 40 + g * 8];
            oT[0][it] = mfma16(av[0], bp, oT[0][it]);
            oT[1][it] = mfma16(av[1], bp, oT[1][it]);
        }
        __builtin_amdgcn_s_setprio(0);

        // rotate double buffers
        if (jc < 7) {
#pragma unroll
            for (int jt = 0; jt < 2; ++jt) ak[jt] = akn[jt];
#pragma unroll
            for (int ct = 0; ct < 2; ++ct) av[ct] = avn[ct];
#pragma unroll
            for (int it = 0; it < 4; ++it) { pc0[it] = pn0[it]; pc1[it] = pn1[it]; }
        }
    }

    float inv[4];
#pragma unroll
    for (int it = 0; it < 4; ++it) {
        float s = lsum[it];
        s += __shfl_xor(s, 16, 64);
        s += __shfl_xor(s, 32, 64);
        inv[it] = rcpv(s);
    }

    __syncthreads();                      // all waves done reading vT
    ushort_t* oT_s = vT;                  // reuse as gated-output transpose buffer
#pragma unroll
    for (int ct = 0; ct < 2; ++ct)
#pragma unroll
        for (int it = 0; it < 4; ++it) {
            const int i = w * 64 + it * 16 + l16;
#pragma unroll
            for (int r = 0; r < 4; ++r) {
                const int c = ct * 16 + g * 4 + r;
                const float gate = bflo((uint_t)gT[c * 264 + i]);
                oT_s[c * 264 + i] = f2bf(oT[ct][it][r] * inv[it] * gate);
            }
        }
    __syncthreads();
    // coalesced bf16x2 store to ao[n*256+i][h*32+c]
    ushort_t* aob = ao + (size_t)n * 256 * 256 + h * 32;
#pragma unroll
    for (int iter = 0; iter < 16; ++iter) {
        const int flat = iter * 256 + t;
        const int i = flat >> 4, cp = flat & 15;
        const uint_t lo = oT_s[(2 * cp) * 264 + i];
        const uint_t hi = oT_s[(2 * cp + 1) * 264 + i];
        *(uint_t*)(aob + (size_t)i * 256 + 2 * cp) = lo | (hi << 16);
    }
}

// -------- K4: out = ao @ Wo + bo (MFMA), row-masked --------
__global__ __launch_bounds__(256, 2) void k_out(const ushort_t* __restrict__ ao,
                                                const ushort_t* __restrict__ woT,
                                                const float* __restrict__ bo,
                                                const int* __restrict__ msa_mask,
                                                float* __restrict__ out) {
    const int t = threadIdx.x;
    const int rb = blockIdx.x * 128;
    const int w = t >> 6, l = t & 63;
    const int l16 = l & 15, g = l >> 4;

#pragma unroll
    for (int ch = 0; ch < 2; ++ch) {
        f32x4 acc[2][8];
#pragma unroll
        for (int rt = 0; rt < 2; ++rt)
#pragma unroll
            for (int ct = 0; ct < 8; ++ct) acc[rt][ct] = (f32x4){0.f, 0.f, 0.f, 0.f};
#pragma unroll
        for (int ks = 0; ks < 8; ++ks) {
            bf16x8 a[2], b[8];
#pragma unroll
            for (int rt = 0; rt < 2; ++rt)
                a[rt] = *(const bf16x8*)(ao + (size_t)(rb + w * 32 + rt * 16 + l16) * 256 + ks * 32 + g * 8);
#pragma unroll
            for (int ct = 0; ct < 8; ++ct)
                b[ct] = *(const bf16x8*)(woT + (size_t)(ch * 128 + ct * 16 + l16) * 256 + ks * 32 + g * 8);
#pragma unroll
            for (int rt = 0; rt < 2; ++rt)
#pragma unroll
                for (int ct = 0; ct < 8; ++ct)
                    acc[rt][ct] = mfma16(a[rt], b[ct], acc[rt][ct]);
        }
#pragma unroll
        for (int rt = 0; rt < 2; ++rt)
#pragma unroll
            for (int ct = 0; ct < 8; ++ct) {
                const int c = ch * 128 + ct * 16 + l16;
                const float boc = bo[c];
#pragma unroll
                for (int r = 0; r < 4; ++r) {
                    const int row = rb + w * 32 + rt * 16 + g * 4 + r;
                    const float mk = msa_mask[row] ? 1.f : 0.f;
                    out[(size_t)row * 256 + c] = (acc[rt][ct][r] + boc) * mk;
                }
            }
    }
}

extern "C" void kernel_launch(void* const* d_in, const int* in_sizes, int n_in,
                              void* d_out, int out_size, void* d_ws, size_t ws_size,
                              hipStream_t stream) {
    const float* m       = (const float*)d_in[0];
    const float* z       = (const float*)d_in[1];
    const int* msa_mask  = (const int*)d_in[2];
    const float* ln_m_g  = (const float*)d_in[3];
    const float* ln_m_b  = (const float*)d_in[4];
    const float* ln_z_g  = (const float*)d_in[5];
    const float* ln_z_b  = (const float*)d_in[6];
    const float* Wq      = (const float*)d_in[7];
    const float* Wk      = (const float*)d_in[8];
    const float* Wv      = (const float*)d_in[9];
    const float* Wb      = (const float*)d_in[10];
    const float* Wg      = (const float*)d_in[11];
    const float* bg      = (const float*)d_in[12];
    const float* Wo      = (const float*)d_in[13];
    const float* bo      = (const float*)d_in[14];
    float* out           = (float*)d_out;

    char* ws = (char*)d_ws;
    ushort_t* mn  = (ushort_t*)(ws);                    // 33,554,432 B
    float*    pb  = (float*)(ws + 33554432);            //  2,097,152 B
    ushort_t* ao  = (ushort_t*)(ws + 35651584);         // 33,554,432 B
    ushort_t* wtT = (ushort_t*)(ws + 69206016);         //    524,288 B
    ushort_t* woT = (ushort_t*)(ws + 69730304);         //    131,072 B

    k_pre<<<17664, 256, 0, stream>>>(m, ln_m_g, ln_m_b, z, ln_z_g, ln_z_b, Wb,
                                     Wq, Wk, Wv, Wg, Wo, mn, pb, wtT, woT);
    k_attn<<<2048, 256, 0, stream>>>(mn, wtT, pb, msa_mask, bg, ao);
    k_out<<<512, 256, 0, stream>>>(ao, woT, bo, msa_mask, out);
}